// Round 2
// baseline (72.717 us; speedup 1.0000x reference)
//
#include <hip/hip_runtime.h>
#include <math.h>

// Problem constants (match reference)
#define BN 32
#define RR 13
#define CC 13
#define AA 5
#define KK 20
#define CELLSZ 25           // K + 5
#define NN (RR * CC * AA)   // 845
#define THRESH 0.5f
#define NMS_TH 0.4f
#define NT 256

__device__ __forceinline__ float sigmoidf_(float x) {
    return 1.0f / (1.0f + expf(-x));
}

// Fully fused: one block per (b,k). Decode batch-b cells straight from x
// (L2-resident, 20x redundant but free), greedy per-class NMS in LDS, write
// this class's score column. Block k==0 also writes bx,by,bw,bh,obj.
__global__ __launch_bounds__(NT) void region_fused_kernel(
        const float* __restrict__ x,
        const float* __restrict__ bias,
        float* __restrict__ out) {
    __shared__ float sx1[NN], sy1[NN], sx2[NN], sy2[NN], sar[NN], ssc[NN];
    __shared__ unsigned char st[NN];   // 0=pending candidate, 1=out, 2=kept
    __shared__ float red_s[NT];
    __shared__ int   red_i[NT];

    const int b   = blockIdx.x / KK;
    const int k   = blockIdx.x % KK;
    const int tid = threadIdx.x;

    // ---- decode straight from x ----
    for (int n = tid; n < NN; n += NT) {
        int r   = n / (CC * AA);
        int rem = n % (CC * AA);
        int c   = rem / AA;
        int a   = rem % AA;
        const float* t = x + (((size_t)(b * RR + r) * CC + c) * AA + a) * CELLSZ;

        float bx  = (sigmoidf_(t[0]) + (float)c) / (float)CC;
        float by  = (sigmoidf_(t[1]) + (float)r) / (float)RR;
        float bw  = expf(t[2]) * bias[2 * a]     / (float)RR;
        float bh  = expf(t[3]) * bias[2 * a + 1] / (float)CC;
        float obj = sigmoidf_(t[4]);

        // softmax over 20 logits: need max + sum, then only class k's prob
        float m = t[5];
#pragma unroll
        for (int j = 1; j < KK; ++j) m = fmaxf(m, t[5 + j]);
        float s = 0.0f;
#pragma unroll
        for (int j = 0; j < KK; ++j) s += expf(t[5 + j] - m);
        float sck = obj * (expf(t[5 + k] - m) / s);

        float x1 = bx - bw * 0.5f;
        float y1 = by - bh * 0.5f;
        sx1[n] = x1;
        sy1[n] = y1;
        sx2[n] = x1 + bw;
        sy2[n] = y1 + bh;
        sar[n] = bw * bh;
        ssc[n] = sck;
        st[n]  = (sck > THRESH) ? 0 : 1;

        if (k == 0) {   // one block per batch owns the box/obj fields
            float* o = out + (size_t)(b * NN + n) * CELLSZ;
            o[0] = bx; o[1] = by; o[2] = bw; o[3] = bh; o[4] = obj;
        }
    }
    __syncthreads();

    // ---- greedy NMS: argmax (lowest index on ties = argsort stability) ----
    while (true) {
        float best = -1.0f;
        int   bi   = 0x7fffffff;
        for (int n = tid; n < NN; n += NT) {
            if (st[n] == 0) {
                float sc = ssc[n];
                if (sc > best) { best = sc; bi = n; }  // ascending n: ties keep lower
            }
        }
        red_s[tid] = best;
        red_i[tid] = bi;
        __syncthreads();
        if (tid < 64) {
            float s0 = red_s[tid];
            int   i0 = red_i[tid];
#pragma unroll
            for (int off = 64; off < NT; off += 64) {
                float so = red_s[tid + off];
                int   io = red_i[tid + off];
                if (so > s0 || (so == s0 && io < i0)) { s0 = so; i0 = io; }
            }
#pragma unroll
            for (int off = 32; off > 0; off >>= 1) {
                float so = __shfl_down(s0, off);
                int   io = __shfl_down(i0, off);
                if (so > s0 || (so == s0 && io < i0)) { s0 = so; i0 = io; }
            }
            if (tid == 0) { red_s[0] = s0; red_i[0] = i0; }
        }
        __syncthreads();
        float bsc = red_s[0];
        int   sel = red_i[0];

        if (bsc < 0.0f) break;   // uniform: no pending candidates left

        if (tid == 0) st[sel] = 2;   // keep

        float X1 = sx1[sel], Y1 = sy1[sel], X2 = sx2[sel], Y2 = sy2[sel];
        float AR = sar[sel];
        for (int n = tid; n < NN; n += NT) {
            if (n != sel && st[n] == 0) {
                float iw = fmaxf(0.0f, fminf(X2, sx2[n]) - fmaxf(X1, sx1[n]));
                float ih = fmaxf(0.0f, fminf(Y2, sy2[n]) - fmaxf(Y1, sy1[n]));
                float inter = iw * ih;
                float uni   = AR + sar[n] - inter;
                float iou   = inter / fmaxf(uni, 1e-9f);
                if (iou > NMS_TH) st[n] = 1;
            }
        }
        __syncthreads();   // st updates (incl. st[sel]=2) visible before next argmax
    }

    // ---- write this class's score column (out is poisoned: write every n) ----
    for (int n = tid; n < NN; n += NT) {
        out[(size_t)(b * NN + n) * CELLSZ + 5 + k] = (st[n] == 2) ? ssc[n] : 0.0f;
    }
}

extern "C" void kernel_launch(void* const* d_in, const int* in_sizes, int n_in,
                              void* d_out, int out_size, void* d_ws, size_t ws_size,
                              hipStream_t stream) {
    const float* x    = (const float*)d_in[0];
    const float* bias = (const float*)d_in[1];
    float* out = (float*)d_out;

    region_fused_kernel<<<BN * KK, NT, 0, stream>>>(x, bias, out);
}

// Round 3
// 62.587 us; speedup vs baseline: 1.1619x; 1.1619x over previous
//
#include <hip/hip_runtime.h>
#include <math.h>

// Problem constants (match reference)
#define BN 32
#define RR 13
#define CC 13
#define AA 5
#define KK 20
#define CELLSZ 25            // K + 5
#define NN (RR * CC * AA)    // 845
#define NBK (BN * KK)        // 640
#define THRESH 0.5f
#define NMS_TH 0.4f

// Workspace layout:
//   int   cnt[NBK]                          @ 0
//   float cand[NBK][CAP][REC]               @ CAND_OFF
// record = { n(as int bits), score, x1, y1, x2, y2, area, pad } = 32 B
#define CAND_OFF 4096
#define REC 8
#define CAP NN               // hard upper bound: <= NN cells per (b,k)

__device__ __forceinline__ float sigmoidf_(float x) {
    return 1.0f / (1.0f + expf(-x));
}

// One thread per (b,n) cell. x/out cell base == idx*25 because
// ((b*R+r)*C+c)*A+a == b*NN + n for n = (r*C+c)*A + a.
__global__ __launch_bounds__(256) void decode_kernel(
        const float* __restrict__ x,
        const float* __restrict__ bias,
        float* __restrict__ out,
        int* __restrict__ cnt,
        float* __restrict__ cand) {
    int idx = blockIdx.x * 256 + threadIdx.x;
    if (idx >= BN * NN) return;
    int b   = idx / NN;
    int n   = idx % NN;
    int r   = n / (CC * AA);
    int rem = n % (CC * AA);
    int c   = rem / AA;
    int a   = rem % AA;

    const float* t = x + (size_t)idx * CELLSZ;

    float bx  = (sigmoidf_(t[0]) + (float)c) / (float)CC;
    float by  = (sigmoidf_(t[1]) + (float)r) / (float)RR;
    float bw  = expf(t[2]) * bias[2 * a]     / (float)RR;
    float bh  = expf(t[3]) * bias[2 * a + 1] / (float)CC;
    float obj = sigmoidf_(t[4]);

    float l[KK];
    float m = t[5];
#pragma unroll
    for (int k = 0; k < KK; ++k) { l[k] = t[5 + k]; m = fmaxf(m, l[k]); }
    float s = 0.0f;
#pragma unroll
    for (int k = 0; k < KK; ++k) { l[k] = expf(l[k] - m); s += l[k]; }

    float* o = out + (size_t)idx * CELLSZ;
    o[0] = bx; o[1] = by; o[2] = bw; o[3] = bh; o[4] = obj;
#pragma unroll
    for (int k = 0; k < KK; ++k) o[5 + k] = 0.0f;   // NMS kernel fills kept ones

    // Rare candidate append (at most one k can exceed 0.5 since softmax sums
    // to 1 and obj < 1, but loop stays general).
#pragma unroll
    for (int k = 0; k < KK; ++k) {
        float p = obj * (l[k] / s);   // same assoc as reference: obj * cls
        if (p > THRESH) {
            int bk   = b * KK + k;
            int slot = atomicAdd(&cnt[bk], 1);   // slot < NN == CAP by construction
            float* rec = cand + ((size_t)bk * CAP + slot) * REC;
            float x1 = bx - bw * 0.5f;
            float y1 = by - bh * 0.5f;
            rec[0] = __int_as_float(n);
            rec[1] = p;
            rec[2] = x1;
            rec[3] = y1;
            rec[4] = x1 + bw;
            rec[5] = y1 + bh;
            rec[6] = bw * bh;
        }
    }
}

// One wave per (b,k): greedy NMS over the m compacted candidates.
// Wave-synchronous (64 threads, no barriers). Argmax tie-breaks on lower box
// index n == reference's stable argsort order; append order irrelevant.
__global__ __launch_bounds__(64) void nms_kernel(
        const int* __restrict__ cnt,
        const float* __restrict__ cand,
        float* __restrict__ out) {
    int bk = blockIdx.x;
    int m  = cnt[bk];
    if (m <= 0) return;
    int b    = bk / KK;
    int k    = bk % KK;
    int lane = threadIdx.x;
    const float* list = cand + (size_t)bk * CAP * REC;

    if (m == 1) {   // fast path: single candidate is always kept
        if (lane == 0) {
            int n = __float_as_int(list[0]);
            out[((size_t)b * NN + n) * CELLSZ + 5 + k] = list[1];
        }
        return;
    }

    int T = (m + 63) >> 6;          // slots per lane (<= 14)
    unsigned alive = 0;
    for (int tt = 0; tt < T; ++tt) {
        int j = lane + (tt << 6);
        if (j < m) alive |= 1u << tt;
    }

    while (true) {
        // local argmax over this lane's alive slots
        float bs = -1.0f;
        int   bn = 0x7fffffff;
        int   bg = -1;
        for (int tt = 0; tt < T; ++tt) {
            if ((alive >> tt) & 1u) {
                int j = lane + (tt << 6);
                float sc = list[j * REC + 1];
                int   nn = __float_as_int(list[j * REC]);
                if (sc > bs || (sc == bs && nn < bn)) { bs = sc; bn = nn; bg = j; }
            }
        }
        // wave butterfly reduce: (score desc, n asc)
#pragma unroll
        for (int off = 32; off > 0; off >>= 1) {
            float os = __shfl_xor(bs, off);
            int   on = __shfl_xor(bn, off);
            int   og = __shfl_xor(bg, off);
            if (os > bs || (os == bs && on < bn)) { bs = os; bn = on; bg = og; }
        }
        if (bg < 0) break;   // uniform: nothing alive

        // winner's box (tiny, L1/L2-hot)
        float X1 = list[bg * REC + 2];
        float Y1 = list[bg * REC + 3];
        float X2 = list[bg * REC + 4];
        float Y2 = list[bg * REC + 5];
        float AR = list[bg * REC + 6];

        if ((bg & 63) == lane) {    // owner keeps it: write score, retire slot
            out[((size_t)b * NN + bn) * CELLSZ + 5 + k] = bs;
            alive &= ~(1u << (bg >> 6));
        }

        // suppress overlapping pending candidates
        for (int tt = 0; tt < T; ++tt) {
            int j = lane + (tt << 6);
            if (((alive >> tt) & 1u) && j != bg) {
                float iw = fmaxf(0.0f, fminf(X2, list[j * REC + 4]) - fmaxf(X1, list[j * REC + 2]));
                float ih = fmaxf(0.0f, fminf(Y2, list[j * REC + 5]) - fmaxf(Y1, list[j * REC + 3]));
                float inter = iw * ih;
                float uni   = AR + list[j * REC + 6] - inter;
                float iou   = inter / fmaxf(uni, 1e-9f);
                if (iou > NMS_TH) alive &= ~(1u << tt);
            }
        }
    }
}

extern "C" void kernel_launch(void* const* d_in, const int* in_sizes, int n_in,
                              void* d_out, int out_size, void* d_ws, size_t ws_size,
                              hipStream_t stream) {
    const float* x    = (const float*)d_in[0];
    const float* bias = (const float*)d_in[1];
    float* out = (float*)d_out;

    int*   cnt  = (int*)d_ws;
    float* cand = (float*)((char*)d_ws + CAND_OFF);

    hipMemsetAsync(cnt, 0, NBK * sizeof(int), stream);   // graph-capturable
    decode_kernel<<<(BN * NN + 255) / 256, 256, 0, stream>>>(x, bias, out, cnt, cand);
    nms_kernel<<<NBK, 64, 0, stream>>>(cnt, cand, out);
}